// Round 3
// baseline (388.294 us; speedup 1.0000x reference)
//
#include <hip/hip_runtime.h>

// CascadedAttentionCell: B=64, T=512, D=1024, OUT=1024 (all fp32 in/out)
// R3: GEMM at 1 wave/SIMD with 512-reg budget: wave tile 128x128 (acc=256 AGPR,
// 4x4 of mfma_f32_32x32x16_f16, 2.0 MFMA/frag-read), block=128 rows x 512 cols
// per pass, grid 256 (1 block/CU). Frees ~250 VGPRs for real load pipelining
// (R2 post-mortem: 124 VGPR + 128 AGPR = 252/256 -> compiler serialized loads).
// k_was_part rewritten: Wa slice in registers, reused across batches (256->4 MB).

typedef _Float16 h8 __attribute__((ext_vector_type(8)));
typedef _Float16 h4 __attribute__((ext_vector_type(4)));
typedef float f16v __attribute__((ext_vector_type(16)));

__device__ __forceinline__ float tanh_fast(float x) {
    float e = __expf(2.0f * x);
    return 1.0f - 2.0f * __builtin_amdgcn_rcpf(e + 1.0f);
}

// ---- pack Ua (fp32 [K=1024][N=1024]) into fp16 B-fragment order ----
// t = ((nt*64+ks)*64) + kg*32 + nn ; thread writes 8 contiguous fp16 (16 B).
__global__ __launch_bounds__(256) void k_pack_ua(const float* __restrict__ Ua,
                                                 _Float16* __restrict__ B16) {
    int t = blockIdx.x * 256 + threadIdx.x;   // 0..131071
    int nn = t & 31, kg = (t >> 5) & 1, ks = (t >> 6) & 63, nt = t >> 12;
    int n = (nt << 5) + nn;
    int kbase = (ks << 4) + (kg << 3);
    h8 v;
#pragma unroll
    for (int j = 0; j < 8; ++j) v[j] = (_Float16)Ua[(size_t)(kbase + j) * 1024 + n];
    *(h8*)(B16 + ((size_t)t << 3)) = v;
}

// ---- WaS partials, Wa-slice-in-registers ----
// grid 32 = (ic<<2 | psl); block 256 thr = 4 waves, wave w handles b in [w*16,+16).
// Each wave holds Wa rows [ic*128+c*32, +32) x its 64-col strip in 128 VGPRs,
// reused across its 16 batches; c=0..3 accumulates via RMW on part (c==0 writes).
__global__ __launch_bounds__(256) void k_was_part(const float* __restrict__ ps,
                                                  const float* __restrict__ Wa,
                                                  float* __restrict__ part) {
    int ic = blockIdx.x >> 2, psl = blockIdx.x & 3;
    int tid = threadIdx.x, wv = tid >> 6, lane = tid & 63;
    int p4 = psl * 64 + lane;                  // float4 column index 0..255
    const float4* Wa4 = (const float4*)Wa;
    float4* part4 = (float4*)part;
#pragma unroll 1
    for (int c = 0; c < 4; ++c) {
        int o0 = ic * 128 + c * 32;
        float4 w[32];
#pragma unroll
        for (int o = 0; o < 32; ++o) w[o] = Wa4[(size_t)(o0 + o) * 256 + p4];
#pragma unroll 1
        for (int bb = 0; bb < 16; ++bb) {
            int b = wv * 16 + bb;
            const float* psb = ps + b * 1024 + o0;
            size_t oidx = (size_t)((ic << 6) + b) * 256 + p4;
            float4 a;
            if (c == 0) { a.x = a.y = a.z = a.w = 0.f; }
            else        { a = part4[oidx]; }
#pragma unroll
            for (int o = 0; o < 32; ++o) {
                float s = psb[o];
                a.x += s * w[o].x; a.y += s * w[o].y;
                a.z += s * w[o].z; a.w += s * w[o].w;
            }
            part4[oidx] = a;
        }
    }
}

// ---- wsWaS[b][p] = Ba[p] + sum_ic part ----
__global__ __launch_bounds__(256) void k_was_reduce(const float* __restrict__ part,
                                                    const float* __restrict__ Ba,
                                                    float* __restrict__ wsWaS) {
    int b = blockIdx.x, tid = threadIdx.x;
    const float4* p4 = (const float4*)part;
    float4 acc = ((const float4*)Ba)[tid];
#pragma unroll
    for (int ic = 0; ic < 8; ++ic) {
        float4 v = p4[((ic << 6) + b) * 256 + tid];
        acc.x += v.x; acc.y += v.y; acc.z += v.z; acc.w += v.w;
    }
    ((float4*)wsWaS)[b * 256 + tid] = acc;
}

// ---- fused GEMM: scores[r] = relu( sum_n tanh(UaH[r][n]+wsWaS[b][n]) * Va[n] ) ----
#define AST 136   // fp16 units; 272 B rows, 16B-aligned
__global__ __launch_bounds__(256, 1) void k_fused_gemm(
    const float* __restrict__ inputs, const _Float16* __restrict__ B16,
    const float* __restrict__ wsWaS, const float* __restrict__ Va,
    float* __restrict__ scores)
{
    __shared__ _Float16 Ash[2][128 * AST];   // 69.6 KB
    __shared__ float scoreSh[128];
    const int tid = threadIdx.x;
    const int lane = tid & 63, wv = tid >> 6;
    const int l31 = lane & 31, lhi = lane >> 5;
    const int r0 = blockIdx.x * 128;
    const int b = r0 >> 9;                    // 4 blocks per batch, never crosses
    const int srow = tid >> 1, sq = tid & 1;  // staging: 2 thr/row, 64 k each
    const float4* srcBase = (const float4*)inputs + (size_t)(r0 + srow) * 256 + sq * 16;

    if (tid < 128) scoreSh[tid] = 0.0f;

    for (int pass = 0; pass < 2; ++pass) {
        const int ntb = (pass << 4) + (wv << 2);   // base n-tile (32 cols each)
        f16v acc[4][4];
#pragma unroll
        for (int rt = 0; rt < 4; ++rt)
#pragma unroll
            for (int ct = 0; ct < 4; ++ct)
#pragma unroll
                for (int e = 0; e < 16; ++e) acc[rt][ct][e] = 0.0f;

        float4 vA[16];
#pragma unroll
        for (int j = 0; j < 16; ++j) vA[j] = srcBase[j];     // kc=0 chunk
        {
            _Float16* dst = &Ash[0][srow * AST + sq * 64];
#pragma unroll
            for (int j = 0; j < 8; ++j) {
                float4 v0 = vA[2 * j], v1 = vA[2 * j + 1];
                *(h8*)(dst + j * 8) = (h8){ (_Float16)v0.x, (_Float16)v0.y,
                                            (_Float16)v0.z, (_Float16)v0.w,
                                            (_Float16)v1.x, (_Float16)v1.y,
                                            (_Float16)v1.z, (_Float16)v1.w };
            }
        }
        __syncthreads();

        for (int kc = 0; kc < 8; ++kc) {
            const int buf = kc & 1;
            if (kc < 7) {                      // HBM loads for next chunk, early
                const float4* s2 = srcBase + ((kc + 1) << 5);
#pragma unroll
                for (int j = 0; j < 16; ++j) vA[j] = s2[j];
            }
#pragma unroll
            for (int ks8 = 0; ks8 < 8; ++ks8) {
                const int ks = (kc << 3) + ks8;
                h8 af[4], bf[4];
#pragma unroll
                for (int rt = 0; rt < 4; ++rt)
                    af[rt] = *(const h8*)&Ash[buf][(rt * 32 + l31) * AST + ks8 * 16 + lhi * 8];
#pragma unroll
                for (int ct = 0; ct < 4; ++ct)
                    bf[ct] = *(const h8*)(B16 + ((((ntb + ct) << 6) + ks) << 9) + lane * 8);
#pragma unroll
                for (int rt = 0; rt < 4; ++rt)
#pragma unroll
                    for (int ct = 0; ct < 4; ++ct)
                        acc[rt][ct] = __builtin_amdgcn_mfma_f32_32x32x16_f16(
                            af[rt], bf[ct], acc[rt][ct], 0, 0, 0);
            }
            if (kc < 7) {                      // loads drained during MFMAs
                _Float16* dst = &Ash[buf ^ 1][srow * AST + sq * 64];
#pragma unroll
                for (int j = 0; j < 8; ++j) {
                    float4 v0 = vA[2 * j], v1 = vA[2 * j + 1];
                    *(h8*)(dst + j * 8) = (h8){ (_Float16)v0.x, (_Float16)v0.y,
                                                (_Float16)v0.z, (_Float16)v0.w,
                                                (_Float16)v1.x, (_Float16)v1.y,
                                                (_Float16)v1.z, (_Float16)v1.w };
                }
            }
            __syncthreads();
        }
        // epilogue: tanh + Va dot over this pass's 128 cols per wave
        float wsv[4], vav[4];
#pragma unroll
        for (int ct = 0; ct < 4; ++ct) {
            int n = (pass << 9) + (wv << 7) + (ct << 5) + l31;
            wsv[ct] = wsWaS[b * 1024 + n];
            vav[ct] = Va[n];
        }
#pragma unroll
        for (int rt = 0; rt < 4; ++rt) {
#pragma unroll
            for (int i = 0; i < 16; ++i) {
                float s = 0.0f;
#pragma unroll
                for (int ct = 0; ct < 4; ++ct)
                    s += tanh_fast(acc[rt][ct][i] + wsv[ct]) * vav[ct];
                s += __shfl_xor(s, 1);
                s += __shfl_xor(s, 2);
                s += __shfl_xor(s, 4);
                s += __shfl_xor(s, 8);
                s += __shfl_xor(s, 16);
                if (l31 == 0) {
                    // 32x32 C/D: row=(reg&3)+8*(reg>>2)+4*(lane>>5)  [m74/m101]
                    int row = rt * 32 + (i & 3) + ((i >> 2) << 3) + (lhi << 2);
                    atomicAdd(&scoreSh[row], s);
                }
            }
        }
    }
    __syncthreads();
    if (tid < 128) scores[r0 + tid] = fmaxf(scoreSh[tid], 0.0f);
}

// ---- softmax over T=512 per batch ----
__global__ __launch_bounds__(256) void k_softmax(const float* __restrict__ scores,
                                                 float* __restrict__ sm) {
    int b = blockIdx.x, tid = threadIdx.x;
    __shared__ float red[256];
    const float* sb = scores + b * 512;
    float s0 = sb[tid], s1 = sb[tid + 256];
    red[tid] = fmaxf(s0, s1);
    __syncthreads();
    for (int st = 128; st > 0; st >>= 1) {
        if (tid < st) red[tid] = fmaxf(red[tid], red[tid + st]);
        __syncthreads();
    }
    float m = red[0];
    __syncthreads();
    float e0 = __expf(s0 - m), e1 = __expf(s1 - m);
    red[tid] = e0 + e1;
    __syncthreads();
    for (int st = 128; st > 0; st >>= 1) {
        if (tid < st) red[tid] += red[tid + st];
        __syncthreads();
    }
    float inv = 1.0f / red[0];
    sm[b * 512 + tid] = e0 * inv;
    sm[b * 512 + 256 + tid] = e1 * inv;
}

// ---- context partials over 64-timestep slices ----
__global__ __launch_bounds__(256) void k_ctx_part(const float* __restrict__ inputs,
                                                  const float* __restrict__ sm,
                                                  float* __restrict__ part) {
    int ts = blockIdx.x, b = blockIdx.y, tid = threadIdx.x;
    const float4* inF4 = (const float4*)inputs;
    float4 acc = {0.f, 0.f, 0.f, 0.f};
    int t0 = ts * 64;
#pragma unroll 8
    for (int t = t0; t < t0 + 64; ++t) {
        float wgt = sm[b * 512 + t];
        float4 x = inF4[(size_t)(b * 512 + t) * 256 + tid];
        acc.x += wgt * x.x; acc.y += wgt * x.y; acc.z += wgt * x.z; acc.w += wgt * x.w;
    }
    ((float4*)part)[((ts << 6) + b) * 256 + tid] = acc;
}

// ---- reduce 8 slices -> d_out ----
__global__ __launch_bounds__(256) void k_ctx_reduce(const float* __restrict__ part,
                                                    float* __restrict__ out) {
    int g = blockIdx.x * 256 + threadIdx.x;
    const float4* p4 = (const float4*)part;
    float4 acc = p4[g];
#pragma unroll
    for (int s = 1; s < 8; ++s) {
        float4 v = p4[s * 16384 + g];
        acc.x += v.x; acc.y += v.y; acc.z += v.z; acc.w += v.w;
    }
    ((float4*)out)[g] = acc;
}

extern "C" void kernel_launch(void* const* d_in, const int* in_sizes, int n_in,
                              void* d_out, int out_size, void* d_ws, size_t ws_size,
                              hipStream_t stream) {
    const float* inputs = (const float*)d_in[0];
    const float* prev   = (const float*)d_in[1];
    const float* Wa     = (const float*)d_in[2];
    const float* Ua     = (const float*)d_in[3];
    const float* Va     = (const float*)d_in[4];
    const float* Ba     = (const float*)d_in[5];
    float* out = (float*)d_out;

    char* ws = (char*)d_ws;
    _Float16* B16   = (_Float16*)(ws);               // 2 MB packed Ua
    float* wasPart  = (float*)(ws + (2u << 20));     // 2 MB
    float* wsWaS    = (float*)(ws + (4u << 20));     // 256 KB
    float* scores   = (float*)(ws + (4u << 20) + (256u << 10));  // 128 KB
    float* sm       = (float*)(ws + (4u << 20) + (384u << 10));  // 128 KB
    float* ctxPart  = (float*)(ws + (4u << 20) + (512u << 10));  // 2 MB

    hipLaunchKernelGGL(k_pack_ua,    dim3(512),    dim3(256), 0, stream, Ua, B16);
    hipLaunchKernelGGL(k_was_part,   dim3(32),     dim3(256), 0, stream, prev, Wa, wasPart);
    hipLaunchKernelGGL(k_was_reduce, dim3(64),     dim3(256), 0, stream, wasPart, Ba, wsWaS);
    hipLaunchKernelGGL(k_fused_gemm, dim3(256),    dim3(256), 0, stream, inputs, B16, wsWaS, Va, scores);
    hipLaunchKernelGGL(k_softmax,    dim3(64),     dim3(256), 0, stream, scores, sm);
    hipLaunchKernelGGL(k_ctx_part,   dim3(8, 64),  dim3(256), 0, stream, inputs, sm, ctxPart);
    hipLaunchKernelGGL(k_ctx_reduce, dim3(64),     dim3(256), 0, stream, ctxPart, out);
}

// Round 4
// 377.917 us; speedup vs baseline: 1.0275x; 1.0275x over previous
//
#include <hip/hip_runtime.h>

// CascadedAttentionCell: B=64, T=512, D=1024, OUT=1024 (all fp32 in/out)
// R4: barrier-free GEMM. Both operands pre-packed to fp16 MFMA-fragment order
// in global memory; GEMM is a pure stream of coalesced global_load_dwordx4 +
// mfma_f32_32x32x16_f16 with an explicit ping-pong register pipeline (loads of
// kstep+1 issued before MFMAs of kstep). No LDS staging, no __syncthreads in
// the K-loop -> nothing forces a vmcnt(0) drain (R1-R3 post-mortem: all three
// staged variants serialized at ~180 cyc/MFMA regardless of registers/occupancy).

typedef _Float16 h8 __attribute__((ext_vector_type(8)));
typedef float f16v __attribute__((ext_vector_type(16)));

__device__ __forceinline__ float tanh_fast(float x) {
    float e = __expf(2.0f * x);
    return 1.0f - 2.0f * __builtin_amdgcn_rcpf(e + 1.0f);
}

// ---- pack Ua (fp32 [K=1024][N=1024]) into fp16 B-fragment order ----
// frag (nt, ks): lane l holds n = nt*32 + (l&31), k = ks*16 + (l>>5)*8 + j.
__global__ __launch_bounds__(256) void k_pack_ua(const float* __restrict__ Ua,
                                                 _Float16* __restrict__ B16) {
    int t = blockIdx.x * 256 + threadIdx.x;   // 0..131071
    int nn = t & 31, kg = (t >> 5) & 1, ks = (t >> 6) & 63, nt = t >> 12;
    int n = (nt << 5) + nn;
    int kbase = (ks << 4) + (kg << 3);
    h8 v;
#pragma unroll
    for (int j = 0; j < 8; ++j) v[j] = (_Float16)Ua[(size_t)(kbase + j) * 1024 + n];
    *(h8*)(B16 + ((size_t)t << 3)) = v;
}

// ---- pack inputs (fp32 [32768 rows][1024]) into fp16 A-fragment order ----
// wave-task w = rb*64 + ks: lane l holds row rb*32+(l&31), k = ks*16+(l>>5)*8+j.
// A16 h8-index = w*64 + lane. Grid 16384 x 256 (4 wave-tasks per block).
__global__ __launch_bounds__(256) void k_pack_a(const float* __restrict__ inputs,
                                                _Float16* __restrict__ A16) {
    int w = blockIdx.x * 4 + (threadIdx.x >> 6);
    int lane = threadIdx.x & 63;
    int rb = w >> 6, ks = w & 63;
    int row = (rb << 5) + (lane & 31);
    int k = (ks << 4) + ((lane >> 5) << 3);
    const float4* src = (const float4*)(inputs + ((size_t)row << 10) + k);
    float4 v0 = src[0], v1 = src[1];
    h8 o = { (_Float16)v0.x, (_Float16)v0.y, (_Float16)v0.z, (_Float16)v0.w,
             (_Float16)v1.x, (_Float16)v1.y, (_Float16)v1.z, (_Float16)v1.w };
    *(h8*)(A16 + (((size_t)w << 6) + lane) * 8) = o;
}

// ---- WaS partials, Wa-slice-in-registers (grid 32) ----
__global__ __launch_bounds__(256) void k_was_part(const float* __restrict__ ps,
                                                  const float* __restrict__ Wa,
                                                  float* __restrict__ part) {
    int ic = blockIdx.x >> 2, psl = blockIdx.x & 3;
    int tid = threadIdx.x, wv = tid >> 6, lane = tid & 63;
    int p4 = psl * 64 + lane;
    const float4* Wa4 = (const float4*)Wa;
    float4* part4 = (float4*)part;
#pragma unroll 1
    for (int c = 0; c < 4; ++c) {
        int o0 = ic * 128 + c * 32;
        float4 w[32];
#pragma unroll
        for (int o = 0; o < 32; ++o) w[o] = Wa4[(size_t)(o0 + o) * 256 + p4];
#pragma unroll 1
        for (int bb = 0; bb < 16; ++bb) {
            int b = wv * 16 + bb;
            const float* psb = ps + b * 1024 + o0;
            size_t oidx = (size_t)((ic << 6) + b) * 256 + p4;
            float4 a;
            if (c == 0) { a.x = a.y = a.z = a.w = 0.f; }
            else        { a = part4[oidx]; }
#pragma unroll
            for (int o = 0; o < 32; ++o) {
                float s = psb[o];
                a.x += s * w[o].x; a.y += s * w[o].y;
                a.z += s * w[o].z; a.w += s * w[o].w;
            }
            part4[oidx] = a;
        }
    }
}

// ---- wsWaS[b][p] = Ba[p] + sum_ic part ----
__global__ __launch_bounds__(256) void k_was_reduce(const float* __restrict__ part,
                                                    const float* __restrict__ Ba,
                                                    float* __restrict__ wsWaS) {
    int b = blockIdx.x, tid = threadIdx.x;
    const float4* p4 = (const float4*)part;
    float4 acc = ((const float4*)Ba)[tid];
#pragma unroll
    for (int ic = 0; ic < 8; ++ic) {
        float4 v = p4[((ic << 6) + b) * 256 + tid];
        acc.x += v.x; acc.y += v.y; acc.z += v.z; acc.w += v.w;
    }
    ((float4*)wsWaS)[b * 256 + tid] = acc;
}

// ---- fused GEMM: scores[r] = relu( sum_n tanh(UaH[r][n]+wsWaS[b][n]) * Va[n] ) ----
// Block: 64 rows (2 frag bands), 4 waves x 128 cols, 2 N-passes. Barrier-free
// K-loop; ping-pong prefetch of (2 A-frag + 4 B-frag) dwordx4 loads.
__global__ __launch_bounds__(256, 2) void k_fused_gemm(
    const _Float16* __restrict__ A16, const _Float16* __restrict__ B16,
    const float* __restrict__ wsWaS, const float* __restrict__ Va,
    float* __restrict__ scores)
{
    __shared__ float scoreSh[64];
    const int tid = threadIdx.x;
    const int lane = tid & 63, wv = tid >> 6;
    const int l31 = lane & 31, lhi = lane >> 5;
    const int r0 = blockIdx.x * 64;
    const int rb0 = blockIdx.x * 2;
    const int b = r0 >> 9;

    if (tid < 64) scoreSh[tid] = 0.0f;
    __syncthreads();

    const h8* A8 = (const h8*)A16;
    const h8* B8 = (const h8*)B16;
    const h8* aBase = A8 + ((size_t)rb0 << 12) + lane;   // frag(rt,ks): +rt*4096+ks*64

    for (int pass = 0; pass < 2; ++pass) {
        const int ntb = (pass << 4) + (wv << 2);
        const h8* bBase = B8 + ((size_t)ntb << 12) + lane;

        f16v acc[2][4];
#pragma unroll
        for (int rt = 0; rt < 2; ++rt)
#pragma unroll
            for (int ct = 0; ct < 4; ++ct)
#pragma unroll
                for (int e = 0; e < 16; ++e) acc[rt][ct][e] = 0.0f;

        h8 af[2][2], bf[2][4];
#pragma unroll
        for (int rt = 0; rt < 2; ++rt) af[0][rt] = aBase[rt * 4096];
#pragma unroll
        for (int ct = 0; ct < 4; ++ct) bf[0][ct] = bBase[ct * 4096];

#pragma unroll 4
        for (int ks = 0; ks < 64; ++ks) {
            const int cur = ks & 1, nxt = cur ^ 1;
            if (ks < 63) {   // issue next k-step's loads before consuming cur
                const int o = (ks + 1) << 6;
#pragma unroll
                for (int rt = 0; rt < 2; ++rt) af[nxt][rt] = aBase[rt * 4096 + o];
#pragma unroll
                for (int ct = 0; ct < 4; ++ct) bf[nxt][ct] = bBase[ct * 4096 + o];
            }
#pragma unroll
            for (int rt = 0; rt < 2; ++rt)
#pragma unroll
                for (int ct = 0; ct < 4; ++ct)
                    acc[rt][ct] = __builtin_amdgcn_mfma_f32_32x32x16_f16(
                        af[cur][rt], bf[cur][ct], acc[rt][ct], 0, 0, 0);
        }

        // epilogue: tanh + Va dot over this wave's 128 cols
        float wsv[4], vav[4];
#pragma unroll
        for (int ct = 0; ct < 4; ++ct) {
            int n = (ntb + ct) << 5 | l31;
            wsv[ct] = wsWaS[b * 1024 + n];
            vav[ct] = Va[n];
        }
#pragma unroll
        for (int rt = 0; rt < 2; ++rt) {
#pragma unroll
            for (int i = 0; i < 16; ++i) {
                float s = 0.0f;
#pragma unroll
                for (int ct = 0; ct < 4; ++ct)
                    s += tanh_fast(acc[rt][ct][i] + wsv[ct]) * vav[ct];
                s += __shfl_xor(s, 1);
                s += __shfl_xor(s, 2);
                s += __shfl_xor(s, 4);
                s += __shfl_xor(s, 8);
                s += __shfl_xor(s, 16);
                if (l31 == 0) {
                    // 32x32 C/D: row=(reg&3)+8*(reg>>2)+4*(lane>>5)  [m74/m101]
                    int row = rt * 32 + (i & 3) + ((i >> 2) << 3) + (lhi << 2);
                    atomicAdd(&scoreSh[row], s);
                }
            }
        }
    }
    __syncthreads();
    if (tid < 64) scores[r0 + tid] = fmaxf(scoreSh[tid], 0.0f);
}

// ---- softmax over T=512 per batch ----
__global__ __launch_bounds__(256) void k_softmax(const float* __restrict__ scores,
                                                 float* __restrict__ sm) {
    int b = blockIdx.x, tid = threadIdx.x;
    __shared__ float red[256];
    const float* sb = scores + b * 512;
    float s0 = sb[tid], s1 = sb[tid + 256];
    red[tid] = fmaxf(s0, s1);
    __syncthreads();
    for (int st = 128; st > 0; st >>= 1) {
        if (tid < st) red[tid] = fmaxf(red[tid], red[tid + st]);
        __syncthreads();
    }
    float m = red[0];
    __syncthreads();
    float e0 = __expf(s0 - m), e1 = __expf(s1 - m);
    red[tid] = e0 + e1;
    __syncthreads();
    for (int st = 128; st > 0; st >>= 1) {
        if (tid < st) red[tid] += red[tid + st];
        __syncthreads();
    }
    float inv = 1.0f / red[0];
    sm[b * 512 + tid] = e0 * inv;
    sm[b * 512 + 256 + tid] = e1 * inv;
}

// ---- context partials over 64-timestep slices ----
__global__ __launch_bounds__(256) void k_ctx_part(const float* __restrict__ inputs,
                                                  const float* __restrict__ sm,
                                                  float* __restrict__ part) {
    int ts = blockIdx.x, b = blockIdx.y, tid = threadIdx.x;
    const float4* inF4 = (const float4*)inputs;
    float4 acc = {0.f, 0.f, 0.f, 0.f};
    int t0 = ts * 64;
#pragma unroll 8
    for (int t = t0; t < t0 + 64; ++t) {
        float wgt = sm[b * 512 + t];
        float4 x = inF4[(size_t)(b * 512 + t) * 256 + tid];
        acc.x += wgt * x.x; acc.y += wgt * x.y; acc.z += wgt * x.z; acc.w += wgt * x.w;
    }
    ((float4*)part)[((ts << 6) + b) * 256 + tid] = acc;
}

// ---- reduce 8 slices -> d_out ----
__global__ __launch_bounds__(256) void k_ctx_reduce(const float* __restrict__ part,
                                                    float* __restrict__ out) {
    int g = blockIdx.x * 256 + threadIdx.x;
    const float4* p4 = (const float4*)part;
    float4 acc = p4[g];
#pragma unroll
    for (int s = 1; s < 8; ++s) {
        float4 v = p4[s * 16384 + g];
        acc.x += v.x; acc.y += v.y; acc.z += v.z; acc.w += v.w;
    }
    ((float4*)out)[g] = acc;
}

extern "C" void kernel_launch(void* const* d_in, const int* in_sizes, int n_in,
                              void* d_out, int out_size, void* d_ws, size_t ws_size,
                              hipStream_t stream) {
    const float* inputs = (const float*)d_in[0];
    const float* prev   = (const float*)d_in[1];
    const float* Wa     = (const float*)d_in[2];
    const float* Ua     = (const float*)d_in[3];
    const float* Va     = (const float*)d_in[4];
    const float* Ba     = (const float*)d_in[5];
    float* out = (float*)d_out;

    char* ws = (char*)d_ws;
    _Float16* A16   = (_Float16*)(ws);                         // 64 MB packed A
    _Float16* B16   = (_Float16*)(ws + (64u << 20));           // 2 MB packed Ua
    float* wasPart  = (float*)(ws + (66u << 20));              // 2 MB
    float* wsWaS    = (float*)(ws + (68u << 20));              // 256 KB
    float* scores   = (float*)(ws + (68u << 20) + (256u << 10));   // 128 KB
    float* sm       = (float*)(ws + (68u << 20) + (384u << 10));   // 128 KB
    float* ctxPart  = (float*)(ws + (68u << 20) + (512u << 10));   // 2 MB

    hipLaunchKernelGGL(k_pack_ua,    dim3(512),    dim3(256), 0, stream, Ua, B16);
    hipLaunchKernelGGL(k_pack_a,     dim3(16384),  dim3(256), 0, stream, inputs, A16);
    hipLaunchKernelGGL(k_was_part,   dim3(32),     dim3(256), 0, stream, prev, Wa, wasPart);
    hipLaunchKernelGGL(k_was_reduce, dim3(64),     dim3(256), 0, stream, wasPart, Ba, wsWaS);
    hipLaunchKernelGGL(k_fused_gemm, dim3(512),    dim3(256), 0, stream, A16, B16, wsWaS, Va, scores);
    hipLaunchKernelGGL(k_softmax,    dim3(64),     dim3(256), 0, stream, scores, sm);
    hipLaunchKernelGGL(k_ctx_part,   dim3(8, 64),  dim3(256), 0, stream, inputs, sm, ctxPart);
    hipLaunchKernelGGL(k_ctx_reduce, dim3(64),     dim3(256), 0, stream, ctxPart, out);
}

// Round 5
// 367.255 us; speedup vs baseline: 1.0573x; 1.0290x over previous
//
#include <hip/hip_runtime.h>

// CascadedAttentionCell: B=64, T=512, D=1024, OUT=1024 (all fp32 in/out)
// R5: barrier-free fragment GEMM + depth-4 A prefetch ring (A frags HBM/L3
// ~600-900cyc; R4's depth-1 only covered ~256-500cyc -> 30% MfmaUtil ceiling).
// B stays depth-1 (L2-resident 2MB). Ring slot ks&3 is copied to locals before
// being overwritten with step ks+4. pack_a fully coalesced; ctx reads fp16 A16
// (fragment layout makes the timestep reduction lane-parallel and coalesced).

typedef _Float16 h8 __attribute__((ext_vector_type(8)));
typedef float f16v __attribute__((ext_vector_type(16)));

__device__ __forceinline__ float tanh_fast(float x) {
    float e = __expf(2.0f * x);
    return 1.0f - 2.0f * __builtin_amdgcn_rcpf(e + 1.0f);
}

// ---- pack Ua (fp32 [K=1024][N=1024]) into fp16 B-fragment order ----
__global__ __launch_bounds__(256) void k_pack_ua(const float* __restrict__ Ua,
                                                 _Float16* __restrict__ B16) {
    int t = blockIdx.x * 256 + threadIdx.x;   // 0..131071
    int nn = t & 31, kg = (t >> 5) & 1, ks = (t >> 6) & 63, nt = t >> 12;
    int n = (nt << 5) + nn;
    int kbase = (ks << 4) + (kg << 3);
    h8 v;
#pragma unroll
    for (int j = 0; j < 8; ++j) v[j] = (_Float16)Ua[(size_t)(kbase + j) * 1024 + n];
    *(h8*)(B16 + ((size_t)t << 3)) = v;
}

// ---- pack inputs into fp16 A-fragment order, coalesced ----
__global__ __launch_bounds__(256) void k_pack_a(const float* __restrict__ inputs,
                                                _Float16* __restrict__ A16) {
    const int bx = blockIdx.x, t = threadIdx.x;
    const int rl = t >> 3, oc0 = t & 7;
    const float4* src = (const float4*)(inputs + (((size_t)bx * 32 + rl) << 10));
    h8* dst = (h8*)A16 + ((size_t)bx << 12) + rl;
#pragma unroll
    for (int i = 0; i < 16; ++i) {
        int o = oc0 + (i << 3);
        float4 v0 = src[o * 2], v1 = src[o * 2 + 1];
        h8 ov = { (_Float16)v0.x, (_Float16)v0.y, (_Float16)v0.z, (_Float16)v0.w,
                  (_Float16)v1.x, (_Float16)v1.y, (_Float16)v1.z, (_Float16)v1.w };
        dst[((o >> 1) << 6) + ((o & 1) << 5)] = ov;
    }
}

// ---- WaS partials, Wa-slice-in-registers (grid 32) ----
__global__ __launch_bounds__(256) void k_was_part(const float* __restrict__ ps,
                                                  const float* __restrict__ Wa,
                                                  float* __restrict__ part) {
    int ic = blockIdx.x >> 2, psl = blockIdx.x & 3;
    int tid = threadIdx.x, wv = tid >> 6, lane = tid & 63;
    int p4 = psl * 64 + lane;
    const float4* Wa4 = (const float4*)Wa;
    float4* part4 = (float4*)part;
#pragma unroll 1
    for (int c = 0; c < 4; ++c) {
        int o0 = ic * 128 + c * 32;
        float4 w[32];
#pragma unroll
        for (int o = 0; o < 32; ++o) w[o] = Wa4[(size_t)(o0 + o) * 256 + p4];
#pragma unroll 1
        for (int bb = 0; bb < 16; ++bb) {
            int b = wv * 16 + bb;
            const float* psb = ps + b * 1024 + o0;
            size_t oidx = (size_t)((ic << 6) + b) * 256 + p4;
            float4 a;
            if (c == 0) { a.x = a.y = a.z = a.w = 0.f; }
            else        { a = part4[oidx]; }
#pragma unroll
            for (int o = 0; o < 32; ++o) {
                float s = psb[o];
                a.x += s * w[o].x; a.y += s * w[o].y;
                a.z += s * w[o].z; a.w += s * w[o].w;
            }
            part4[oidx] = a;
        }
    }
}

// ---- wsWaS[b][p] = Ba[p] + sum_ic part ----
__global__ __launch_bounds__(256) void k_was_reduce(const float* __restrict__ part,
                                                    const float* __restrict__ Ba,
                                                    float* __restrict__ wsWaS) {
    int b = blockIdx.x, tid = threadIdx.x;
    const float4* p4 = (const float4*)part;
    float4 acc = ((const float4*)Ba)[tid];
#pragma unroll
    for (int ic = 0; ic < 8; ++ic) {
        float4 v = p4[((ic << 6) + b) * 256 + tid];
        acc.x += v.x; acc.y += v.y; acc.z += v.z; acc.w += v.w;
    }
    ((float4*)wsWaS)[b * 256 + tid] = acc;
}

// ---- fused GEMM, barrier-free K-loop, depth-4 A ring + depth-1 B ping-pong ----
__global__ __launch_bounds__(256, 2) void k_fused_gemm(
    const _Float16* __restrict__ A16, const _Float16* __restrict__ B16,
    const float* __restrict__ wsWaS, const float* __restrict__ Va,
    float* __restrict__ scores)
{
    __shared__ float scoreSh[64];
    const int tid = threadIdx.x;
    const int lane = tid & 63, wv = tid >> 6;
    const int l31 = lane & 31, lhi = lane >> 5;
    const int r0 = blockIdx.x * 64;
    const int rb0 = blockIdx.x * 2;
    const int b = r0 >> 9;

    if (tid < 64) scoreSh[tid] = 0.0f;
    __syncthreads();

    const h8* A8 = (const h8*)A16;
    const h8* B8 = (const h8*)B16;
    const h8* aBase = A8 + ((size_t)rb0 << 12) + lane;

    for (int pass = 0; pass < 2; ++pass) {
        const int ntb = (pass << 4) + (wv << 2);
        const h8* bBase = B8 + ((size_t)ntb << 12) + lane;

        f16v acc[2][4];
#pragma unroll
        for (int rt = 0; rt < 2; ++rt)
#pragma unroll
            for (int ct = 0; ct < 4; ++ct)
#pragma unroll
                for (int e = 0; e < 16; ++e) acc[rt][ct][e] = 0.0f;

        h8 af[4][2], bf[2][4];
#pragma unroll
        for (int p = 0; p < 4; ++p)
#pragma unroll
            for (int rt = 0; rt < 2; ++rt) af[p][rt] = aBase[rt * 4096 + p * 64];
#pragma unroll
        for (int ct = 0; ct < 4; ++ct) bf[0][ct] = bBase[ct * 4096];

#pragma unroll 4
        for (int ks = 0; ks < 64; ++ks) {
            const int cur = ks & 1, nxt = cur ^ 1, ra = ks & 3;
            // copy current A frags out of the ring before overwriting the slot
            h8 a0 = af[ra][0], a1 = af[ra][1];
            if (ks < 60) {           // A for ks+4 (HBM/L3 latency, ~4-iter cover)
                const int o = (ks + 4) << 6;
                af[ra][0] = aBase[o];
                af[ra][1] = aBase[4096 + o];
            }
            if (ks < 63) {           // B for ks+1 (L2-resident, 1-iter cover)
                const int o = (ks + 1) << 6;
#pragma unroll
                for (int ct = 0; ct < 4; ++ct) bf[nxt][ct] = bBase[ct * 4096 + o];
            }
#pragma unroll
            for (int ct = 0; ct < 4; ++ct) {
                acc[0][ct] = __builtin_amdgcn_mfma_f32_32x32x16_f16(a0, bf[cur][ct], acc[0][ct], 0, 0, 0);
                acc[1][ct] = __builtin_amdgcn_mfma_f32_32x32x16_f16(a1, bf[cur][ct], acc[1][ct], 0, 0, 0);
            }
        }

        float wsv[4], vav[4];
#pragma unroll
        for (int ct = 0; ct < 4; ++ct) {
            int n = (ntb + ct) << 5 | l31;
            wsv[ct] = wsWaS[b * 1024 + n];
            vav[ct] = Va[n];
        }
#pragma unroll
        for (int rt = 0; rt < 2; ++rt) {
#pragma unroll
            for (int i = 0; i < 16; ++i) {
                float s = 0.0f;
#pragma unroll
                for (int ct = 0; ct < 4; ++ct)
                    s += tanh_fast(acc[rt][ct][i] + wsv[ct]) * vav[ct];
                s += __shfl_xor(s, 1);
                s += __shfl_xor(s, 2);
                s += __shfl_xor(s, 4);
                s += __shfl_xor(s, 8);
                s += __shfl_xor(s, 16);
                if (l31 == 0) {
                    // 32x32 C/D: row=(reg&3)+8*(reg>>2)+4*(lane>>5)  [m74/m101]
                    int row = rt * 32 + (i & 3) + ((i >> 2) << 3) + (lhi << 2);
                    atomicAdd(&scoreSh[row], s);
                }
            }
        }
    }
    __syncthreads();
    if (tid < 64) scores[r0 + tid] = fmaxf(scoreSh[tid], 0.0f);
}

// ---- softmax over T=512 per batch ----
__global__ __launch_bounds__(256) void k_softmax(const float* __restrict__ scores,
                                                 float* __restrict__ sm) {
    int b = blockIdx.x, tid = threadIdx.x;
    __shared__ float red[256];
    const float* sb = scores + b * 512;
    float s0 = sb[tid], s1 = sb[tid + 256];
    red[tid] = fmaxf(s0, s1);
    __syncthreads();
    for (int st = 128; st > 0; st >>= 1) {
        if (tid < st) red[tid] = fmaxf(red[tid], red[tid + st]);
        __syncthreads();
    }
    float m = red[0];
    __syncthreads();
    float e0 = __expf(s0 - m), e1 = __expf(s1 - m);
    red[tid] = e0 + e1;
    __syncthreads();
    for (int st = 128; st > 0; st >>= 1) {
        if (tid < st) red[tid] += red[tid + st];
        __syncthreads();
    }
    float inv = 1.0f / red[0];
    sm[b * 512 + tid] = e0 * inv;
    sm[b * 512 + 256 + tid] = e1 * inv;
}

// ---- ctx from packed fp16 A16 ----
__global__ __launch_bounds__(256) void k_ctx(const _Float16* __restrict__ A16,
                                             const float* __restrict__ sm,
                                             float* __restrict__ out) {
    const int bx = blockIdx.x, b = blockIdx.y;
    const int tid = threadIdx.x, wv = tid >> 6, lane = tid & 63;
    const int l31 = lane & 31, lhi = lane >> 5;
    const h8* A8 = (const h8*)A16;
    const int ksl = bx * 4 + wv;
    float facc[8];
#pragma unroll
    for (int j = 0; j < 8; ++j) facc[j] = 0.0f;
    const float* smb = sm + b * 512;
#pragma unroll 4
    for (int rbl = 0; rbl < 16; ++rbl) {
        h8 x = A8[(((size_t)(b * 16 + rbl) << 6) + ksl) * 64 + lane];
        float wgt = smb[rbl * 32 + l31];
#pragma unroll
        for (int j = 0; j < 8; ++j) facc[j] += wgt * (float)x[j];
    }
#pragma unroll
    for (int m = 1; m < 32; m <<= 1)
#pragma unroll
        for (int j = 0; j < 8; ++j) facc[j] += __shfl_xor(facc[j], m);
    if (l31 == 0) {
        int oct = bx * 8 + wv * 2 + lhi;
        float* o = out + b * 1024 + oct * 8;
#pragma unroll
        for (int j = 0; j < 8; ++j) o[j] = facc[j];
    }
}

extern "C" void kernel_launch(void* const* d_in, const int* in_sizes, int n_in,
                              void* d_out, int out_size, void* d_ws, size_t ws_size,
                              hipStream_t stream) {
    const float* inputs = (const float*)d_in[0];
    const float* prev   = (const float*)d_in[1];
    const float* Wa     = (const float*)d_in[2];
    const float* Ua     = (const float*)d_in[3];
    const float* Va     = (const float*)d_in[4];
    const float* Ba     = (const float*)d_in[5];
    float* out = (float*)d_out;

    char* ws = (char*)d_ws;
    _Float16* A16   = (_Float16*)(ws);                         // 64 MB packed A
    _Float16* B16   = (_Float16*)(ws + (64u << 20));           // 2 MB packed Ua
    float* wasPart  = (float*)(ws + (66u << 20));              // 2 MB
    float* wsWaS    = (float*)(ws + (68u << 20));              // 256 KB
    float* scores   = (float*)(ws + (68u << 20) + (256u << 10));   // 128 KB
    float* sm       = (float*)(ws + (68u << 20) + (384u << 10));   // 128 KB

    hipLaunchKernelGGL(k_pack_ua,    dim3(512),    dim3(256), 0, stream, Ua, B16);
    hipLaunchKernelGGL(k_pack_a,     dim3(1024),   dim3(256), 0, stream, inputs, A16);
    hipLaunchKernelGGL(k_was_part,   dim3(32),     dim3(256), 0, stream, prev, Wa, wasPart);
    hipLaunchKernelGGL(k_was_reduce, dim3(64),     dim3(256), 0, stream, wasPart, Ba, wsWaS);
    hipLaunchKernelGGL(k_fused_gemm, dim3(512),    dim3(256), 0, stream, A16, B16, wsWaS, Va, scores);
    hipLaunchKernelGGL(k_softmax,    dim3(64),     dim3(256), 0, stream, scores, sm);
    hipLaunchKernelGGL(k_ctx,        dim3(16, 64), dim3(256), 0, stream, A16, sm, out);
}